// Round 2
// baseline (1732.451 us; speedup 1.0000x reference)
//
#include <hip/hip_runtime.h>
#include <math.h>

// ---------------- CSR build ----------------

__global__ void k_hist(const int* __restrict__ dst, int* __restrict__ deg, int E){
  int e = blockIdx.x * blockDim.x + threadIdx.x;
  if (e < E) atomicAdd(&deg[dst[e]], 1);
}

__global__ __launch_bounds__(1024) void k_scan(int* __restrict__ degcur, int* __restrict__ offs, int N, int E){
  __shared__ int sm[1024];
  int tid = threadIdx.x;
  int carry = 0;
  for (int base = 0; base < N; base += 1024){
    int i = base + tid;
    int v = (i < N) ? degcur[i] : 0;
    sm[tid] = v;
    __syncthreads();
    for (int o = 1; o < 1024; o <<= 1){
      int t = (tid >= o) ? sm[tid - o] : 0;
      __syncthreads();
      sm[tid] += t;
      __syncthreads();
    }
    int incl = sm[tid];
    if (i < N){
      int excl = carry + incl - v;
      offs[i] = excl;      // exclusive prefix
      degcur[i] = excl;    // becomes the running insert cursor
    }
    carry += sm[1023];
    __syncthreads();
  }
  if (tid == 0) offs[N] = E;
}

__global__ void k_fill(const int* __restrict__ src, const int* __restrict__ dstv,
                       int* __restrict__ cursor, int* __restrict__ srclist, int E){
  int e = blockIdx.x * blockDim.x + threadIdx.x;
  if (e < E){
    int d = dstv[e];
    int pos = atomicAdd(&cursor[d], 1);
    srclist[pos] = src[e];
  }
}

// ---------------- fused q/k/v/skip projections ----------------

__global__ __launch_bounds__(256) void k_proj(const float* __restrict__ hin, int fi, int N, int fo,
    const float* __restrict__ Wq, const float* __restrict__ bq,
    const float* __restrict__ Wk, const float* __restrict__ bk,
    const float* __restrict__ Wv, const float* __restrict__ bv,
    const float* __restrict__ Wsk, const float* __restrict__ bsk,
    float* __restrict__ qo, float* __restrict__ ko, float* __restrict__ vo, float* __restrict__ so)
{
  extern __shared__ float ws[];
  const int ldw = fi + 1;
  const int BM = 64;
  int blockRow = blockIdx.x * BM;
  const float* Warr[4] = {Wq, Wk, Wv, Wsk};
  const float* barr[4] = {bq, bk, bv, bsk};
  float* oarr[4] = {qo, ko, vo, so};
  for (int sel = 0; sel < 4; ++sel){
    const float* W = Warr[sel];
    const float* b = barr[sel];
    float* out = oarr[sel];
    for (int idx = threadIdx.x; idx < fo * fi; idx += blockDim.x){
      int n = idx / fi, kk = idx - n * fi;
      ws[n * ldw + kk] = W[idx];
    }
    __syncthreads();
    int total = BM * fo;
    for (int oi = threadIdx.x; oi < total; oi += blockDim.x){
      int r = oi / fo, n = oi - r * fo;
      int row = blockRow + r;
      if (row < N){
        const float* x = hin + (size_t)row * fi;
        const float* wr = ws + n * ldw;
        float acc = b[n];
        #pragma unroll 4
        for (int kk = 0; kk < fi; ++kk) acc = fmaf(x[kk], wr[kk], acc);
        out[(size_t)row * fo + n] = acc;
      }
    }
    __syncthreads();
  }
}

// ---------------- per-node online-softmax attention ----------------

__global__ __launch_bounds__(256) void k_attn(const float* __restrict__ q, const float* __restrict__ k,
    const float* __restrict__ v, const int* __restrict__ offs, const int* __restrict__ srclist,
    float* __restrict__ hout, int N, int fo, float scale, int relu)
{
  int wid = blockIdx.x * (blockDim.x >> 6) + (threadIdx.x >> 6);
  int lane = threadIdx.x & 63;
  if (wid >= N) return;
  int d0 = lane, d1 = 64 + lane;
  bool p0 = d0 < fo, p1 = d1 < fo;
  const float* qi = q + (size_t)wid * fo;
  float q0 = p0 ? qi[d0] : 0.f;
  float q1 = p1 ? qi[d1] : 0.f;
  float m = -INFINITY, l = 0.f, a0 = 0.f, a1 = 0.f;
  int e0 = offs[wid], e1 = offs[wid + 1];
  for (int e = e0; e < e1; ++e){
    int j = srclist[e];
    const float* kj = k + (size_t)j * fo;
    const float* vj = v + (size_t)j * fo;
    float kk0 = p0 ? kj[d0] : 0.f;
    float kk1 = p1 ? kj[d1] : 0.f;
    float v0 = p0 ? vj[d0] : 0.f;
    float v1 = p1 ? vj[d1] : 0.f;
    float part = q0 * kk0 + q1 * kk1;
    #pragma unroll
    for (int o = 32; o; o >>= 1) part += __shfl_xor(part, o);
    float s = part * scale;
    float mnew = fmaxf(m, s);
    float sfac = __expf(m - mnew);   // first iter: exp(-inf)=0
    float p = __expf(s - mnew);
    l = l * sfac + p;
    a0 = a0 * sfac + p * v0;
    a1 = a1 * sfac + p * v1;
    m = mnew;
  }
  float inv = 1.f / fmaxf(l, 1e-16f);   // isolated nodes -> agg 0
  float* ho = hout + (size_t)wid * fo;
  if (p0){
    float val = ho[d0] + a0 * inv;
    if (relu) val = fmaxf(val, 0.f);
    ho[d0] = val;
  }
  if (p1){
    float val = ho[d1] + a1 * inv;
    if (relu) val = fmaxf(val, 0.f);
    ho[d1] = val;
  }
}

// ---------------- row log_softmax over 32 classes (in place) ----------------

__global__ __launch_bounds__(256) void k_lsm(float* __restrict__ out, int N){
  int row = blockIdx.x * (blockDim.x >> 5) + (threadIdx.x >> 5);
  int c = threadIdx.x & 31;
  if (row >= N) return;
  float z = out[(size_t)row * 32 + c];
  float mx = z;
  #pragma unroll
  for (int o = 16; o; o >>= 1) mx = fmaxf(mx, __shfl_xor(mx, o, 32));
  float e = __expf(z - mx);
  float ssum = e;
  #pragma unroll
  for (int o = 16; o; o >>= 1) ssum += __shfl_xor(ssum, o, 32);
  out[(size_t)row * 32 + c] = z - mx - logf(ssum);
}

// ---------------- launch ----------------

extern "C" void kernel_launch(void* const* d_in, const int* in_sizes, int n_in,
                              void* d_out, int out_size, void* d_ws, size_t ws_size,
                              hipStream_t stream)
{
  const float* x  = (const float*)d_in[0];
  const int*   ei = (const int*)d_in[1];
  const int N = in_sizes[0] / 128;
  const int E = in_sizes[1] / 2;

  const float* W1[4]; const float* b1[4];
  const float* W2[4]; const float* b2[4];
  const float* W3[4]; const float* b3[4];
  for (int i = 0; i < 4; ++i){
    W1[i] = (const float*)d_in[2 + i];   b1[i] = (const float*)d_in[6 + i];
    W2[i] = (const float*)d_in[10 + i];  b2[i] = (const float*)d_in[14 + i];
    W3[i] = (const float*)d_in[18 + i];  b3[i] = (const float*)d_in[22 + i];
  }

  float* wsf = (float*)d_ws;
  auto a64 = [](size_t v){ return (v + 63) & ~(size_t)63; };
  size_t off = 0;
  int* offs    = (int*)(wsf + off); off += a64((size_t)N + 1);
  int* cursor  = (int*)(wsf + off); off += a64((size_t)N);
  int* srclist = (int*)(wsf + off); off += a64((size_t)E);
  float* qb = wsf + off; off += a64((size_t)N * 96);
  float* kb = wsf + off; off += a64((size_t)N * 96);
  float* vb = wsf + off; off += a64((size_t)N * 96);
  float* hA = wsf + off; off += a64((size_t)N * 96);
  float* hB = wsf + off; off += a64((size_t)N * 96);

  // --- CSR of incoming edges (by dst, store src) ---
  hipMemsetAsync(cursor, 0, (size_t)N * sizeof(int), stream);
  k_hist<<<dim3((E + 255) / 256), dim3(256), 0, stream>>>(ei + E, cursor, E);
  k_scan<<<dim3(1), dim3(1024), 0, stream>>>(cursor, offs, N, E);
  k_fill<<<dim3((E + 255) / 256), dim3(256), 0, stream>>>(ei, ei + E, cursor, srclist, E);

  // --- layers ---
  auto layer = [&](const float* hin, int fi, int fo, const float** W, const float** b,
                   float* hout, int relu){
    int gridP = (N + 63) / 64;
    size_t lds = (size_t)fo * (fi + 1) * sizeof(float);
    k_proj<<<dim3(gridP), dim3(256), lds, stream>>>(hin, fi, N, fo,
        W[0], b[0], W[1], b[1], W[2], b[2], W[3], b[3], qb, kb, vb, hout);
    int gridA = (N + 3) / 4;
    float scale = 1.0f / sqrtf((float)fo);
    k_attn<<<dim3(gridA), dim3(256), 0, stream>>>(qb, kb, vb, offs, srclist, hout,
        N, fo, scale, relu);
  };

  float* outf = (float*)d_out;
  layer(x,  128, 96, W1, b1, hA, 1);
  layer(hA,  96, 96, W2, b2, hB, 1);
  layer(hB,  96, 32, W3, b3, outf, 0);

  k_lsm<<<dim3((N + 7) / 8), dim3(256), 0, stream>>>(outf, N);
}

// Round 3
// 676.857 us; speedup vs baseline: 2.5596x; 2.5596x over previous
//
#include <hip/hip_runtime.h>
#include <math.h>

typedef __attribute__((ext_vector_type(8))) __bf16 bf16x8;
typedef __attribute__((ext_vector_type(8))) short short8;
typedef __attribute__((ext_vector_type(4))) float f32x4;
typedef unsigned int uint;
typedef unsigned short ushort;

// ---------------- helpers ----------------

__device__ inline bf16x8 ld_bf8(const ushort* p){
  short8 s = *reinterpret_cast<const short8*>(p);
  return __builtin_bit_cast(bf16x8, s);
}

__device__ inline ushort f2bf(float f){
  uint u = __builtin_bit_cast(uint, f);
  uint r = (u + 0x7FFFu + ((u >> 16) & 1u)) >> 16;
  return (ushort)r;
}

__device__ inline float bf_lo(uint u){ return __builtin_bit_cast(float, u << 16); }
__device__ inline float bf_hi(uint u){ return __builtin_bit_cast(float, u & 0xFFFF0000u); }

// ---------------- CSR build ----------------

__global__ void k_hist(const int* __restrict__ dst, int* __restrict__ deg, int E){
  int e = blockIdx.x * blockDim.x + threadIdx.x;
  if (e < E) atomicAdd(&deg[dst[e]], 1);
}

__global__ __launch_bounds__(1024) void k_scan(int* __restrict__ degcur, int* __restrict__ offs, int N, int E){
  __shared__ int sm[1024];
  int tid = threadIdx.x;
  int carry = 0;
  for (int base = 0; base < N; base += 1024){
    int i = base + tid;
    int v = (i < N) ? degcur[i] : 0;
    sm[tid] = v;
    __syncthreads();
    for (int o = 1; o < 1024; o <<= 1){
      int t = (tid >= o) ? sm[tid - o] : 0;
      __syncthreads();
      sm[tid] += t;
      __syncthreads();
    }
    int incl = sm[tid];
    if (i < N){
      int excl = carry + incl - v;
      offs[i] = excl;
      degcur[i] = excl;
    }
    carry += sm[1023];
    __syncthreads();
  }
  if (tid == 0) offs[N] = E;
}

__global__ void k_fill(const int* __restrict__ src, const int* __restrict__ dstv,
                       int* __restrict__ cursor, int* __restrict__ srclist, int E){
  int e = blockIdx.x * blockDim.x + threadIdx.x;
  if (e < E){
    int d = dstv[e];
    int pos = atomicAdd(&cursor[d], 1);
    srclist[pos] = src[e];
  }
}

// ---------------- casts ----------------

// fp32 -> bf16 bits, vectorized x4 (n divisible by 4)
__global__ __launch_bounds__(256) void k_castv(const float* __restrict__ in, ushort* __restrict__ out, int n4){
  int i = blockIdx.x * blockDim.x + threadIdx.x;
  int stride = gridDim.x * blockDim.x;
  for (; i < n4; i += stride){
    const float4 v = reinterpret_cast<const float4*>(in)[i];
    ushort4 o;
    o.x = f2bf(v.x); o.y = f2bf(v.y); o.z = f2bf(v.z); o.w = f2bf(v.w);
    reinterpret_cast<ushort4*>(out)[i] = o;
  }
}

struct WSet { const float* src[12]; ushort* dst[12]; int n[12]; };

__global__ __launch_bounds__(256) void k_castw(WSet ws){
  int m = blockIdx.y;
  int n = ws.n[m];
  const float* s = ws.src[m];
  ushort* d = ws.dst[m];
  for (int i = blockIdx.x * blockDim.x + threadIdx.x; i < n; i += gridDim.x * blockDim.x)
    d[i] = f2bf(s[i]);
}

// ---------------- MFMA projections ----------------
// Block = 4 waves; wave w computes matrix w of {q,k,v,skip}.
// Weights held in registers (bf16 frags); grid-stride over 16-row tiles.
// A-frag: lane holds hin[row0 + (lane&15)][kt*32 + (lane>>4)*8 + 0..7]
// B-frag: lane holds W  [n0   + (lane&15)][kt*32 + (lane>>4)*8 + 0..7]   (W = B^T)
// D: col = lane&15 (n), row = (lane>>4)*4 + reg (m)   [m89-verified]

template<int KT, int NT>
__global__ __launch_bounds__(256) void k_projmfma(
    const ushort* __restrict__ hin, int N,
    const ushort* __restrict__ Wq, const ushort* __restrict__ Wk,
    const ushort* __restrict__ Wv, const ushort* __restrict__ Wsk,
    const float* __restrict__ bq, const float* __restrict__ bk,
    const float* __restrict__ bv, const float* __restrict__ bs,
    ushort* __restrict__ qo, ushort* __restrict__ ko, ushort* __restrict__ vo,
    float* __restrict__ so)
{
  constexpr int K  = KT * 32;
  constexpr int FO = NT * 16;
  const int wv   = threadIdx.x >> 6;
  const int lane = threadIdx.x & 63;
  const int r16  = lane & 15;
  const int kg   = lane >> 4;

  const ushort* W = (wv == 0) ? Wq : (wv == 1) ? Wk : (wv == 2) ? Wv : Wsk;
  const float*  b = (wv == 0) ? bq : (wv == 1) ? bk : (wv == 2) ? bv : bs;

  bf16x8 bf[NT][KT];
  #pragma unroll
  for (int nt = 0; nt < NT; ++nt)
    #pragma unroll
    for (int kt = 0; kt < KT; ++kt)
      bf[nt][kt] = ld_bf8(W + (size_t)(nt * 16 + r16) * K + kt * 32 + kg * 8);

  float biasv[NT];
  #pragma unroll
  for (int nt = 0; nt < NT; ++nt) biasv[nt] = b[nt * 16 + r16];

  const int MT = N >> 4;
  for (int mt = blockIdx.x; mt < MT; mt += gridDim.x){
    const int row0 = mt * 16;
    bf16x8 af[KT];
    #pragma unroll
    for (int kt = 0; kt < KT; ++kt)
      af[kt] = ld_bf8(hin + (size_t)(row0 + r16) * K + kt * 32 + kg * 8);

    f32x4 acc[NT];
    #pragma unroll
    for (int nt = 0; nt < NT; ++nt){
      acc[nt][0] = biasv[nt]; acc[nt][1] = biasv[nt];
      acc[nt][2] = biasv[nt]; acc[nt][3] = biasv[nt];
    }
    #pragma unroll
    for (int nt = 0; nt < NT; ++nt)
      #pragma unroll
      for (int kt = 0; kt < KT; ++kt)
        acc[nt] = __builtin_amdgcn_mfma_f32_16x16x32_bf16(af[kt], bf[nt][kt], acc[nt], 0, 0, 0);

    if (wv < 3){
      ushort* out = (wv == 0) ? qo : (wv == 1) ? ko : vo;
      #pragma unroll
      for (int nt = 0; nt < NT; ++nt)
        #pragma unroll
        for (int i = 0; i < 4; ++i)
          out[(size_t)(row0 + kg * 4 + i) * FO + nt * 16 + r16] = f2bf(acc[nt][i]);
    } else {
      #pragma unroll
      for (int nt = 0; nt < NT; ++nt)
        #pragma unroll
        for (int i = 0; i < 4; ++i)
          so[(size_t)(row0 + kg * 4 + i) * FO + nt * 16 + r16] = acc[nt][i];
    }
  }
}

// ---------------- per-node online-softmax attention (bf16 q/k/v) ----------------
// 1 wave/node; lane l (< fo/2) holds packed elems (2l, 2l+1) of each row.

__global__ __launch_bounds__(256) void k_attn(const ushort* __restrict__ qb, const ushort* __restrict__ kb,
    const ushort* __restrict__ vb, const int* __restrict__ offs, const int* __restrict__ srclist,
    float* __restrict__ hout, int N, int fo, float scale, int relu)
{
  int wid = blockIdx.x * (blockDim.x >> 6) + (threadIdx.x >> 6);
  int lane = threadIdx.x & 63;
  if (wid >= N) return;
  const int L = fo >> 1;
  const bool act = lane < L;

  uint qw = act ? reinterpret_cast<const uint*>(qb + (size_t)wid * fo)[lane] : 0u;
  float q0 = bf_lo(qw), q1 = bf_hi(qw);

  float m = -INFINITY, l = 0.f, a0 = 0.f, a1 = 0.f;
  int e0 = offs[wid], e1 = offs[wid + 1];
  for (int e = e0; e < e1; ++e){
    int j = srclist[e];
    uint kw = act ? reinterpret_cast<const uint*>(kb + (size_t)j * fo)[lane] : 0u;
    uint vw = act ? reinterpret_cast<const uint*>(vb + (size_t)j * fo)[lane] : 0u;
    float part = q0 * bf_lo(kw) + q1 * bf_hi(kw);
    #pragma unroll
    for (int o = 32; o; o >>= 1) part += __shfl_xor(part, o);
    float s = part * scale;
    float mnew = fmaxf(m, s);
    float sfac = __expf(m - mnew);
    float p = __expf(s - mnew);
    l = l * sfac + p;
    a0 = a0 * sfac + p * bf_lo(vw);
    a1 = a1 * sfac + p * bf_hi(vw);
    m = mnew;
  }
  float inv = 1.f / fmaxf(l, 1e-16f);
  if (act){
    float* ho = hout + (size_t)wid * fo + 2 * lane;
    float v0 = ho[0] + a0 * inv;
    float v1 = ho[1] + a1 * inv;
    if (relu){ v0 = fmaxf(v0, 0.f); v1 = fmaxf(v1, 0.f); }
    ho[0] = v0; ho[1] = v1;
  }
}

// ---------------- row log_softmax over 32 classes (in place) ----------------

__global__ __launch_bounds__(256) void k_lsm(float* __restrict__ out, int N){
  int row = blockIdx.x * (blockDim.x >> 5) + (threadIdx.x >> 5);
  int c = threadIdx.x & 31;
  if (row >= N) return;
  float z = out[(size_t)row * 32 + c];
  float mx = z;
  #pragma unroll
  for (int o = 16; o; o >>= 1) mx = fmaxf(mx, __shfl_xor(mx, o, 32));
  float e = __expf(z - mx);
  float ssum = e;
  #pragma unroll
  for (int o = 16; o; o >>= 1) ssum += __shfl_xor(ssum, o, 32);
  out[(size_t)row * 32 + c] = z - mx - logf(ssum);
}

// ---------------- launch ----------------

extern "C" void kernel_launch(void* const* d_in, const int* in_sizes, int n_in,
                              void* d_out, int out_size, void* d_ws, size_t ws_size,
                              hipStream_t stream)
{
  const float* x  = (const float*)d_in[0];
  const int*   ei = (const int*)d_in[1];
  const int N = in_sizes[0] / 128;
  const int E = in_sizes[1] / 2;

  const float* W1[4]; const float* b1[4];
  const float* W2[4]; const float* b2[4];
  const float* W3[4]; const float* b3[4];
  for (int i = 0; i < 4; ++i){
    W1[i] = (const float*)d_in[2 + i];   b1[i] = (const float*)d_in[6 + i];
    W2[i] = (const float*)d_in[10 + i];  b2[i] = (const float*)d_in[14 + i];
    W3[i] = (const float*)d_in[18 + i];  b3[i] = (const float*)d_in[22 + i];
  }

  // byte-granular workspace allocator, 256B aligned
  size_t off = 0;
  auto alloc = [&](size_t bytes) -> void* {
    void* p = (char*)d_ws + off;
    off = (off + bytes + 255) & ~(size_t)255;
    return p;
  };
  int* offs    = (int*)alloc(((size_t)N + 1) * 4);
  int* cursor  = (int*)alloc((size_t)N * 4);
  int* srclist = (int*)alloc((size_t)E * 4);
  ushort* qb = (ushort*)alloc((size_t)N * 96 * 2);
  ushort* kb = (ushort*)alloc((size_t)N * 96 * 2);
  ushort* vb = (ushort*)alloc((size_t)N * 96 * 2);
  float*  hF = (float*)alloc((size_t)N * 96 * 4);
  ushort* hb = (ushort*)alloc((size_t)N * 128 * 2);
  ushort* wb = (ushort*)alloc((size_t)98304 * 2);

  // bf16 weight pointers
  ushort* Wb1[4]; ushort* Wb2[4]; ushort* Wb3[4];
  for (int i = 0; i < 4; ++i){
    Wb1[i] = wb + (size_t)i * 12288;
    Wb2[i] = wb + 49152 + (size_t)i * 9216;
    Wb3[i] = wb + 49152 + 36864 + (size_t)i * 3072;
  }

  // --- weight casts (once) ---
  WSet wset;
  for (int i = 0; i < 4; ++i){
    wset.src[i]     = W1[i]; wset.dst[i]     = Wb1[i]; wset.n[i]     = 12288;
    wset.src[4 + i] = W2[i]; wset.dst[4 + i] = Wb2[i]; wset.n[4 + i] = 9216;
    wset.src[8 + i] = W3[i]; wset.dst[8 + i] = Wb3[i]; wset.n[8 + i] = 3072;
  }
  k_castw<<<dim3(48, 12), dim3(256), 0, stream>>>(wset);

  // --- CSR of incoming edges ---
  hipMemsetAsync(cursor, 0, (size_t)N * sizeof(int), stream);
  k_hist<<<dim3((E + 255) / 256), dim3(256), 0, stream>>>(ei + E, cursor, E);
  k_scan<<<dim3(1), dim3(1024), 0, stream>>>(cursor, offs, N, E);
  k_fill<<<dim3((E + 255) / 256), dim3(256), 0, stream>>>(ei, ei + E, cursor, srclist, E);

  // --- input cast ---
  k_castv<<<dim3(2048), dim3(256), 0, stream>>>(x, hb, N * 128 / 4);

  float* outf = (float*)d_out;

  // --- layer 1: K=128 (KT=4), fo=96 (NT=6) ---
  k_projmfma<4, 6><<<dim3(1024), dim3(256), 0, stream>>>(hb, N,
      Wb1[0], Wb1[1], Wb1[2], Wb1[3], b1[0], b1[1], b1[2], b1[3], qb, kb, vb, hF);
  k_attn<<<dim3((N + 3) / 4), dim3(256), 0, stream>>>(qb, kb, vb, offs, srclist, hF,
      N, 96, 1.0f / sqrtf(96.f), 1);
  k_castv<<<dim3(2048), dim3(256), 0, stream>>>(hF, hb, N * 96 / 4);

  // --- layer 2: K=96 (KT=3), fo=96 (NT=6) ---
  k_projmfma<3, 6><<<dim3(1024), dim3(256), 0, stream>>>(hb, N,
      Wb2[0], Wb2[1], Wb2[2], Wb2[3], b2[0], b2[1], b2[2], b2[3], qb, kb, vb, hF);
  k_attn<<<dim3((N + 3) / 4), dim3(256), 0, stream>>>(qb, kb, vb, offs, srclist, hF,
      N, 96, 1.0f / sqrtf(96.f), 1);
  k_castv<<<dim3(2048), dim3(256), 0, stream>>>(hF, hb, N * 96 / 4);

  // --- layer 3: K=96 (KT=3), fo=32 (NT=2) ---
  k_projmfma<3, 2><<<dim3(1024), dim3(256), 0, stream>>>(hb, N,
      Wb3[0], Wb3[1], Wb3[2], Wb3[3], b3[0], b3[1], b3[2], b3[3], qb, kb, vb, outf);
  k_attn<<<dim3((N + 3) / 4), dim3(256), 0, stream>>>(qb, kb, vb, offs, srclist, outf,
      N, 32, 1.0f / sqrtf(32.f), 0);

  k_lsm<<<dim3((N + 7) / 8), dim3(256), 0, stream>>>(outf, N);
}

// Round 4
// 396.807 us; speedup vs baseline: 4.3660x; 1.7058x over previous
//
#include <hip/hip_runtime.h>
#include <math.h>

typedef __attribute__((ext_vector_type(8))) __bf16 bf16x8;
typedef __attribute__((ext_vector_type(8))) short short8;
typedef __attribute__((ext_vector_type(4))) float f32x4;
typedef unsigned int uint;
typedef unsigned short ushort;

// ---------------- helpers ----------------

__device__ inline bf16x8 ld_bf8(const ushort* p){
  short8 s = *reinterpret_cast<const short8*>(p);
  return __builtin_bit_cast(bf16x8, s);
}

__device__ inline ushort f2bf(float f){
  uint u = __builtin_bit_cast(uint, f);
  uint r = (u + 0x7FFFu + ((u >> 16) & 1u)) >> 16;
  return (ushort)r;
}

__device__ inline float bf_lo(uint u){ return __builtin_bit_cast(float, u << 16); }
__device__ inline float bf_hi(uint u){ return __builtin_bit_cast(float, u & 0xFFFF0000u); }
__device__ inline float bfu(ushort u){ return __builtin_bit_cast(float, (uint)u << 16); }

// ---------------- CSR build ----------------

__global__ void k_hist(const int* __restrict__ dst, int* __restrict__ deg, int E){
  int e = blockIdx.x * blockDim.x + threadIdx.x;
  if (e < E) atomicAdd(&deg[dst[e]], 1);
}

// 1 block, chunked: each thread scans a contiguous chunk serially, one
// 1024-wide Hillis-Steele for the chunk sums (10 barriers total).
__global__ __launch_bounds__(1024) void k_scan(int* __restrict__ deg, int* __restrict__ offs, int N, int E){
  __shared__ int sm[1024];
  const int tid = threadIdx.x;
  const int CH = (N + 1023) >> 10;
  int b0 = tid * CH;
  int b1 = b0 + CH; if (b1 > N) b1 = N;
  int s = 0;
  for (int i = b0; i < b1; ++i) s += deg[i];
  sm[tid] = s;
  __syncthreads();
  for (int o = 1; o < 1024; o <<= 1){
    int t = (tid >= o) ? sm[tid - o] : 0;
    __syncthreads();
    sm[tid] += t;
    __syncthreads();
  }
  int run = sm[tid] - s;   // exclusive prefix of this chunk
  for (int i = b0; i < b1; ++i){
    int d = deg[i];
    offs[i] = run;
    deg[i] = run;          // becomes insert cursor
    run += d;
  }
  if (tid == 0) offs[N] = E;
}

__global__ void k_fill(const int* __restrict__ src, const int* __restrict__ dstv,
                       int* __restrict__ cursor, int* __restrict__ srclist, int E){
  int e = blockIdx.x * blockDim.x + threadIdx.x;
  if (e < E){
    int d = dstv[e];
    int pos = atomicAdd(&cursor[d], 1);
    srclist[pos] = src[e];
  }
}

// ---------------- casts ----------------

__global__ __launch_bounds__(256) void k_castv(const float* __restrict__ in, ushort* __restrict__ out, int n4){
  int i = blockIdx.x * blockDim.x + threadIdx.x;
  int stride = gridDim.x * blockDim.x;
  for (; i < n4; i += stride){
    const float4 v = reinterpret_cast<const float4*>(in)[i];
    ushort4 o;
    o.x = f2bf(v.x); o.y = f2bf(v.y); o.z = f2bf(v.z); o.w = f2bf(v.w);
    reinterpret_cast<ushort4*>(out)[i] = o;
  }
}

struct WSet { const float* src[12]; ushort* dst[12]; int n[12]; };

__global__ __launch_bounds__(256) void k_castw(WSet ws){
  int m = blockIdx.y;
  int n = ws.n[m];
  const float* s = ws.src[m];
  ushort* d = ws.dst[m];
  for (int i = blockIdx.x * blockDim.x + threadIdx.x; i < n; i += gridDim.x * blockDim.x)
    d[i] = f2bf(s[i]);
}

// ---------------- MFMA projections ----------------
// Block = 4 waves; wave w computes matrix w of {q,k,v,skip}.
// k and v are written interleaved into kv rows (stride kvst = 2*FO).

template<int KT, int NT>
__global__ __launch_bounds__(256) void k_projmfma(
    const ushort* __restrict__ hin, int N,
    const ushort* __restrict__ Wq, const ushort* __restrict__ Wk,
    const ushort* __restrict__ Wv, const ushort* __restrict__ Wsk,
    const float* __restrict__ bq, const float* __restrict__ bk,
    const float* __restrict__ bv, const float* __restrict__ bs,
    ushort* __restrict__ qo, ushort* __restrict__ ko, ushort* __restrict__ vo,
    int kvst, float* __restrict__ so)
{
  constexpr int K  = KT * 32;
  constexpr int FO = NT * 16;
  const int wv   = threadIdx.x >> 6;
  const int lane = threadIdx.x & 63;
  const int r16  = lane & 15;
  const int kg   = lane >> 4;

  const ushort* W = (wv == 0) ? Wq : (wv == 1) ? Wk : (wv == 2) ? Wv : Wsk;
  const float*  b = (wv == 0) ? bq : (wv == 1) ? bk : (wv == 2) ? bv : bs;

  bf16x8 bf[NT][KT];
  #pragma unroll
  for (int nt = 0; nt < NT; ++nt)
    #pragma unroll
    for (int kt = 0; kt < KT; ++kt)
      bf[nt][kt] = ld_bf8(W + (size_t)(nt * 16 + r16) * K + kt * 32 + kg * 8);

  float biasv[NT];
  #pragma unroll
  for (int nt = 0; nt < NT; ++nt) biasv[nt] = b[nt * 16 + r16];

  const int MT = N >> 4;
  for (int mt = blockIdx.x; mt < MT; mt += gridDim.x){
    const int row0 = mt * 16;
    bf16x8 af[KT];
    #pragma unroll
    for (int kt = 0; kt < KT; ++kt)
      af[kt] = ld_bf8(hin + (size_t)(row0 + r16) * K + kt * 32 + kg * 8);

    f32x4 acc[NT];
    #pragma unroll
    for (int nt = 0; nt < NT; ++nt){
      acc[nt][0] = biasv[nt]; acc[nt][1] = biasv[nt];
      acc[nt][2] = biasv[nt]; acc[nt][3] = biasv[nt];
    }
    #pragma unroll
    for (int nt = 0; nt < NT; ++nt)
      #pragma unroll
      for (int kt = 0; kt < KT; ++kt)
        acc[nt] = __builtin_amdgcn_mfma_f32_16x16x32_bf16(af[kt], bf[nt][kt], acc[nt], 0, 0, 0);

    if (wv < 3){
      ushort* out = (wv == 0) ? qo : (wv == 1) ? ko : vo;
      const int st = (wv == 0) ? FO : kvst;
      #pragma unroll
      for (int nt = 0; nt < NT; ++nt)
        #pragma unroll
        for (int i = 0; i < 4; ++i)
          out[(size_t)(row0 + kg * 4 + i) * st + nt * 16 + r16] = f2bf(acc[nt][i]);
    } else {
      #pragma unroll
      for (int nt = 0; nt < NT; ++nt)
        #pragma unroll
        for (int i = 0; i < 4; ++i)
          so[(size_t)(row0 + kg * 4 + i) * FO + nt * 16 + r16] = acc[nt][i];
    }
  }
}

// ---------------- attention: multi-node waves, batched edges ----------------
// G = lanes per node group (32 for FO=96, 16 for FO=32); LPN = FO/4 active
// lanes, each holding 4 contiguous features. Butterfly shuffles stay inside
// the group (masks < G). 4 edges per iteration, next batch prefetched.
// MODE 0: out = bf16(relu(skip+agg)) [next layer input]
// MODE 1: out = fp32 log_softmax(skip+agg) [final]

template<int FO, int G, int MODE>
__global__ __launch_bounds__(256) void k_attn2(
    const ushort* __restrict__ qb, const ushort* __restrict__ kv,
    const float* __restrict__ skip, const int* __restrict__ offs,
    const int* __restrict__ srclist, void* __restrict__ outp,
    int N, float scale)
{
  constexpr int LPN = FO / 4;
  constexpr int KVW = 2 * FO;
  constexpr int GPW = 64 / G;
  const int lane = threadIdx.x & 63;
  const int sub  = lane & (G - 1);
  const int gid  = lane / G;
  const int node = (blockIdx.x * (blockDim.x >> 6) + (threadIdx.x >> 6)) * GPW + gid;
  const bool nv  = node < N;
  const bool act = nv && (sub < LPN);
  const int sub2 = (sub < LPN) ? sub : 0;
  const int nodec = nv ? node : 0;

  ushort4 qw = *reinterpret_cast<const ushort4*>(qb + (size_t)nodec * FO + sub2 * 4);
  float qf[4];
  qf[0] = act ? bfu(qw.x) : 0.f;
  qf[1] = act ? bfu(qw.y) : 0.f;
  qf[2] = act ? bfu(qw.z) : 0.f;
  qf[3] = act ? bfu(qw.w) : 0.f;

  float m = -INFINITY, l = 0.f;
  float acc[4] = {0.f, 0.f, 0.f, 0.f};
  int e0 = nv ? offs[node] : 0;
  int e1 = nv ? offs[node + 1] : 0;

  uint2 kk[4], vv[4];
  auto LOAD = [&](int eb, uint2* K, uint2* V){
    #pragma unroll
    for (int i = 0; i < 4; ++i){
      int ee = eb + i;
      int ec = (ee < e1) ? ee : (e1 - 1);
      int j = srclist[ec];
      const ushort* r = kv + (size_t)j * KVW + sub2 * 4;
      K[i] = *reinterpret_cast<const uint2*>(r);
      V[i] = *reinterpret_cast<const uint2*>(r + FO);
    }
  };

  if (e0 < e1){
    LOAD(e0, kk, vv);
    for (int e = e0; e < e1; ){
      const int en = e + 4;
      const bool more = en < e1;
      uint2 kn[4], vn[4];
      if (more) LOAD(en, kn, vn);

      float s[4];
      #pragma unroll
      for (int i = 0; i < 4; ++i){
        uint a_ = kk[i].x, b_ = kk[i].y;
        s[i] = qf[0] * bf_lo(a_) + qf[1] * bf_hi(a_)
             + qf[2] * bf_lo(b_) + qf[3] * bf_hi(b_);
      }
      #pragma unroll
      for (int o = 1; o < G; o <<= 1){
        s[0] += __shfl_xor(s[0], o);
        s[1] += __shfl_xor(s[1], o);
        s[2] += __shfl_xor(s[2], o);
        s[3] += __shfl_xor(s[3], o);
      }
      s[0] = s[0] * scale;
      s[1] = (e + 1 < e1) ? s[1] * scale : -1e30f;
      s[2] = (e + 2 < e1) ? s[2] * scale : -1e30f;
      s[3] = (e + 3 < e1) ? s[3] * scale : -1e30f;

      float mnew = fmaxf(fmaxf(m, s[0]), fmaxf(fmaxf(s[1], s[2]), s[3]));
      float sfac = __expf(m - mnew);
      float p[4];
      p[0] = __expf(s[0] - mnew);
      p[1] = __expf(s[1] - mnew);   // invalid -> exp(-huge) = 0
      p[2] = __expf(s[2] - mnew);
      p[3] = __expf(s[3] - mnew);
      l = l * sfac + (p[0] + p[1]) + (p[2] + p[3]);
      acc[0] *= sfac; acc[1] *= sfac; acc[2] *= sfac; acc[3] *= sfac;
      #pragma unroll
      for (int i = 0; i < 4; ++i){
        uint a_ = vv[i].x, b_ = vv[i].y;
        acc[0] = fmaf(p[i], bf_lo(a_), acc[0]);
        acc[1] = fmaf(p[i], bf_hi(a_), acc[1]);
        acc[2] = fmaf(p[i], bf_lo(b_), acc[2]);
        acc[3] = fmaf(p[i], bf_hi(b_), acc[3]);
      }
      m = mnew;
      e = en;
      if (more){
        #pragma unroll
        for (int i = 0; i < 4; ++i){ kk[i] = kn[i]; vv[i] = vn[i]; }
      }
    }
  }

  float inv = 1.f / fmaxf(l, 1e-16f);
  const float4 sv = *reinterpret_cast<const float4*>(skip + (size_t)nodec * FO + sub2 * 4);
  float val[4];
  val[0] = sv.x + acc[0] * inv;
  val[1] = sv.y + acc[1] * inv;
  val[2] = sv.z + acc[2] * inv;
  val[3] = sv.w + acc[3] * inv;

  if (MODE == 0){
    if (act){
      ushort4 o;
      o.x = f2bf(fmaxf(val[0], 0.f));
      o.y = f2bf(fmaxf(val[1], 0.f));
      o.z = f2bf(fmaxf(val[2], 0.f));
      o.w = f2bf(fmaxf(val[3], 0.f));
      *reinterpret_cast<ushort4*>((ushort*)outp + (size_t)node * FO + sub * 4) = o;
    }
  } else {
    float mx = act ? fmaxf(fmaxf(val[0], val[1]), fmaxf(val[2], val[3])) : -INFINITY;
    #pragma unroll
    for (int o = 1; o < G; o <<= 1) mx = fmaxf(mx, __shfl_xor(mx, o));
    float ssum = 0.f;
    if (act){
      ssum = __expf(val[0] - mx) + __expf(val[1] - mx)
           + __expf(val[2] - mx) + __expf(val[3] - mx);
    }
    #pragma unroll
    for (int o = 1; o < G; o <<= 1) ssum += __shfl_xor(ssum, o);
    float lg = __logf(ssum);
    if (act){
      float4 o;
      o.x = val[0] - mx - lg;
      o.y = val[1] - mx - lg;
      o.z = val[2] - mx - lg;
      o.w = val[3] - mx - lg;
      *reinterpret_cast<float4*>((float*)outp + (size_t)node * FO + sub * 4) = o;
    }
  }
}

// ---------------- launch ----------------

extern "C" void kernel_launch(void* const* d_in, const int* in_sizes, int n_in,
                              void* d_out, int out_size, void* d_ws, size_t ws_size,
                              hipStream_t stream)
{
  const float* x  = (const float*)d_in[0];
  const int*   ei = (const int*)d_in[1];
  const int N = in_sizes[0] / 128;
  const int E = in_sizes[1] / 2;

  const float* W1[4]; const float* b1[4];
  const float* W2[4]; const float* b2[4];
  const float* W3[4]; const float* b3[4];
  for (int i = 0; i < 4; ++i){
    W1[i] = (const float*)d_in[2 + i];   b1[i] = (const float*)d_in[6 + i];
    W2[i] = (const float*)d_in[10 + i];  b2[i] = (const float*)d_in[14 + i];
    W3[i] = (const float*)d_in[18 + i];  b3[i] = (const float*)d_in[22 + i];
  }

  size_t off = 0;
  auto alloc = [&](size_t bytes) -> void* {
    void* p = (char*)d_ws + off;
    off = (off + bytes + 255) & ~(size_t)255;
    return p;
  };
  int* offs    = (int*)alloc(((size_t)N + 1) * 4);
  int* cursor  = (int*)alloc((size_t)N * 4);
  int* srclist = (int*)alloc((size_t)E * 4);
  ushort* qb = (ushort*)alloc((size_t)N * 96 * 2);
  ushort* kvb = (ushort*)alloc((size_t)N * 192 * 2);
  float*  hF = (float*)alloc((size_t)N * 96 * 4);
  ushort* hb = (ushort*)alloc((size_t)N * 128 * 2);
  ushort* wb = (ushort*)alloc((size_t)98304 * 2);

  ushort* Wb1[4]; ushort* Wb2[4]; ushort* Wb3[4];
  for (int i = 0; i < 4; ++i){
    Wb1[i] = wb + (size_t)i * 12288;
    Wb2[i] = wb + 49152 + (size_t)i * 9216;
    Wb3[i] = wb + 49152 + 36864 + (size_t)i * 3072;
  }

  WSet wset;
  for (int i = 0; i < 4; ++i){
    wset.src[i]     = W1[i]; wset.dst[i]     = Wb1[i]; wset.n[i]     = 12288;
    wset.src[4 + i] = W2[i]; wset.dst[4 + i] = Wb2[i]; wset.n[4 + i] = 9216;
    wset.src[8 + i] = W3[i]; wset.dst[8 + i] = Wb3[i]; wset.n[8 + i] = 3072;
  }
  k_castw<<<dim3(48, 12), dim3(256), 0, stream>>>(wset);

  hipMemsetAsync(cursor, 0, (size_t)N * sizeof(int), stream);
  k_hist<<<dim3((E + 255) / 256), dim3(256), 0, stream>>>(ei + E, cursor, E);
  k_scan<<<dim3(1), dim3(1024), 0, stream>>>(cursor, offs, N, E);
  k_fill<<<dim3((E + 255) / 256), dim3(256), 0, stream>>>(ei, ei + E, cursor, srclist, E);

  k_castv<<<dim3(2048), dim3(256), 0, stream>>>(x, hb, N * 128 / 4);

  float* outf = (float*)d_out;
  const float sc96 = 1.0f / sqrtf(96.f);
  const float sc32 = 1.0f / sqrtf(32.f);

  // layer 1: K=128, FO=96
  k_projmfma<4, 6><<<dim3(1024), dim3(256), 0, stream>>>(hb, N,
      Wb1[0], Wb1[1], Wb1[2], Wb1[3], b1[0], b1[1], b1[2], b1[3],
      qb, kvb, kvb + 96, 192, hF);
  k_attn2<96, 32, 0><<<dim3(N / 8), dim3(256), 0, stream>>>(qb, kvb, hF, offs, srclist, hb, N, sc96);

  // layer 2: K=96, FO=96
  k_projmfma<3, 6><<<dim3(1024), dim3(256), 0, stream>>>(hb, N,
      Wb2[0], Wb2[1], Wb2[2], Wb2[3], b2[0], b2[1], b2[2], b2[3],
      qb, kvb, kvb + 96, 192, hF);
  k_attn2<96, 32, 0><<<dim3(N / 8), dim3(256), 0, stream>>>(qb, kvb, hF, offs, srclist, hb, N, sc96);

  // layer 3: K=96, FO=32 (+ fused log_softmax)
  k_projmfma<3, 2><<<dim3(1024), dim3(256), 0, stream>>>(hb, N,
      Wb3[0], Wb3[1], Wb3[2], Wb3[3], b3[0], b3[1], b3[2], b3[3],
      qb, kvb, kvb + 32, 64, hF);
  k_attn2<32, 16, 1><<<dim3(N / 16), dim3(256), 0, stream>>>(qb, kvb, hF, offs, srclist, outf, N, sc32);
}

// Round 5
// 294.481 us; speedup vs baseline: 5.8831x; 1.3475x over previous
//
#include <hip/hip_runtime.h>
#include <math.h>

typedef __attribute__((ext_vector_type(8))) __bf16 bf16x8;
typedef __attribute__((ext_vector_type(8))) short short8;
typedef __attribute__((ext_vector_type(4))) float f32x4;
typedef unsigned int uint;
typedef unsigned short ushort;

// ---------------- helpers ----------------

__device__ inline bf16x8 ld_bf8(const ushort* p){
  short8 s = *reinterpret_cast<const short8*>(p);
  return __builtin_bit_cast(bf16x8, s);
}

__device__ inline ushort f2bf(float f){
  uint u = __builtin_bit_cast(uint, f);
  uint r = (u + 0x7FFFu + ((u >> 16) & 1u)) >> 16;
  return (ushort)r;
}

__device__ inline float bf_lo(uint u){ return __builtin_bit_cast(float, u << 16); }
__device__ inline float bf_hi(uint u){ return __builtin_bit_cast(float, u & 0xFFFF0000u); }
__device__ inline float bfu(ushort u){ return __builtin_bit_cast(float, (uint)u << 16); }

// ---------------- CSR build ----------------

__global__ void k_hist(const int* __restrict__ dst, int* __restrict__ deg, int E){
  int e = blockIdx.x * blockDim.x + threadIdx.x;
  if (e < E) atomicAdd(&deg[dst[e]], 1);
}

// phase 1: per-block (1024 elems) sums, int4-coalesced
__global__ __launch_bounds__(256) void k_scan_part(const int* __restrict__ deg, int* __restrict__ bsum, int N){
  int base = blockIdx.x * 1024 + threadIdx.x * 4;
  int s = 0;
  if (base + 3 < N){
    int4 v = *reinterpret_cast<const int4*>(deg + base);
    s = v.x + v.y + v.z + v.w;
  } else {
    for (int i = base; i < N && i < base + 4; ++i) s += deg[i];
  }
  #pragma unroll
  for (int o = 32; o; o >>= 1) s += __shfl_xor(s, o);
  __shared__ int sm[4];
  if ((threadIdx.x & 63) == 0) sm[threadIdx.x >> 6] = s;
  __syncthreads();
  if (threadIdx.x == 0) bsum[blockIdx.x] = sm[0] + sm[1] + sm[2] + sm[3];
}

// phase 2: one wave scans the block sums (exclusive), nb <= 1024
__global__ __launch_bounds__(64) void k_scan_mid(int* __restrict__ bsum, int nb){
  int lane = threadIdx.x;
  int chunk = (nb + 63) >> 6;
  int b0 = lane * chunk;
  int b1 = b0 + chunk; if (b1 > nb) b1 = nb;
  int s = 0;
  for (int i = b0; i < b1; ++i) s += bsum[i];
  int incl = s;
  #pragma unroll
  for (int o = 1; o < 64; o <<= 1){
    int t = __shfl_up(incl, o);
    if (lane >= o) incl += t;
  }
  int run = incl - s;
  for (int i = b0; i < b1; ++i){
    int d = bsum[i];
    bsum[i] = run;
    run += d;
  }
}

// phase 3: block-local scan + block offset -> offs (exclusive), deg := cursor
__global__ __launch_bounds__(256) void k_scan_add(int* __restrict__ deg, int* __restrict__ offs,
                                                  const int* __restrict__ bsum, int N, int E){
  int base = blockIdx.x * 1024 + threadIdx.x * 4;
  int v0 = 0, v1 = 0, v2 = 0, v3 = 0;
  if (base + 3 < N){
    int4 v = *reinterpret_cast<const int4*>(deg + base);
    v0 = v.x; v1 = v.y; v2 = v.z; v3 = v.w;
  } else {
    if (base     < N) v0 = deg[base];
    if (base + 1 < N) v1 = deg[base + 1];
    if (base + 2 < N) v2 = deg[base + 2];
    if (base + 3 < N) v3 = deg[base + 3];
  }
  int s = v0 + v1 + v2 + v3;
  int lane = threadIdx.x & 63, wv = threadIdx.x >> 6;
  int incl = s;
  #pragma unroll
  for (int o = 1; o < 64; o <<= 1){
    int t = __shfl_up(incl, o);
    if (lane >= o) incl += t;
  }
  __shared__ int wsum[4];
  if (lane == 63) wsum[wv] = incl;
  __syncthreads();
  int woff = 0;
  for (int w = 0; w < wv; ++w) woff += wsum[w];
  int excl = bsum[blockIdx.x] + woff + incl - s;
  if (base     < N){ offs[base]     = excl; deg[base]     = excl; excl += v0; }
  if (base + 1 < N){ offs[base + 1] = excl; deg[base + 1] = excl; excl += v1; }
  if (base + 2 < N){ offs[base + 2] = excl; deg[base + 2] = excl; excl += v2; }
  if (base + 3 < N){ offs[base + 3] = excl; deg[base + 3] = excl; excl += v3; }
  if (blockIdx.x == 0 && threadIdx.x == 0) offs[N] = E;
}

__global__ void k_fill(const int* __restrict__ src, const int* __restrict__ dstv,
                       int* __restrict__ cursor, int* __restrict__ srclist, int E){
  int e = blockIdx.x * blockDim.x + threadIdx.x;
  if (e < E){
    int d = dstv[e];
    int pos = atomicAdd(&cursor[d], 1);
    srclist[pos] = src[e];
  }
}

// ---------------- casts ----------------

__global__ __launch_bounds__(256) void k_castv(const float* __restrict__ in, ushort* __restrict__ out, int n4){
  int i = blockIdx.x * blockDim.x + threadIdx.x;
  int stride = gridDim.x * blockDim.x;
  for (; i < n4; i += stride){
    const float4 v = reinterpret_cast<const float4*>(in)[i];
    ushort4 o;
    o.x = f2bf(v.x); o.y = f2bf(v.y); o.z = f2bf(v.z); o.w = f2bf(v.w);
    reinterpret_cast<ushort4*>(out)[i] = o;
  }
}

struct WSet { const float* src[12]; ushort* dst[12]; int n[12]; };

__global__ __launch_bounds__(256) void k_castw(WSet ws){
  int m = blockIdx.y;
  int n = ws.n[m];
  const float* s = ws.src[m];
  ushort* d = ws.dst[m];
  for (int i = blockIdx.x * blockDim.x + threadIdx.x; i < n; i += gridDim.x * blockDim.x)
    d[i] = f2bf(s[i]);
}

// ---------------- MFMA projections ----------------
// Block = 4 waves; wave w computes matrix w of {q,k,v,skip}.
// k and v are written interleaved into kv rows (stride kvst = 2*FO).

template<int KT, int NT>
__global__ __launch_bounds__(256) void k_projmfma(
    const ushort* __restrict__ hin, int N,
    const ushort* __restrict__ Wq, const ushort* __restrict__ Wk,
    const ushort* __restrict__ Wv, const ushort* __restrict__ Wsk,
    const float* __restrict__ bq, const float* __restrict__ bk,
    const float* __restrict__ bv, const float* __restrict__ bs,
    ushort* __restrict__ qo, ushort* __restrict__ ko, ushort* __restrict__ vo,
    int kvst, float* __restrict__ so)
{
  constexpr int K  = KT * 32;
  constexpr int FO = NT * 16;
  const int wv   = threadIdx.x >> 6;
  const int lane = threadIdx.x & 63;
  const int r16  = lane & 15;
  const int kg   = lane >> 4;

  const ushort* W = (wv == 0) ? Wq : (wv == 1) ? Wk : (wv == 2) ? Wv : Wsk;
  const float*  b = (wv == 0) ? bq : (wv == 1) ? bk : (wv == 2) ? bv : bs;

  bf16x8 bf[NT][KT];
  #pragma unroll
  for (int nt = 0; nt < NT; ++nt)
    #pragma unroll
    for (int kt = 0; kt < KT; ++kt)
      bf[nt][kt] = ld_bf8(W + (size_t)(nt * 16 + r16) * K + kt * 32 + kg * 8);

  float biasv[NT];
  #pragma unroll
  for (int nt = 0; nt < NT; ++nt) biasv[nt] = b[nt * 16 + r16];

  const int MT = N >> 4;
  for (int mt = blockIdx.x; mt < MT; mt += gridDim.x){
    const int row0 = mt * 16;
    bf16x8 af[KT];
    #pragma unroll
    for (int kt = 0; kt < KT; ++kt)
      af[kt] = ld_bf8(hin + (size_t)(row0 + r16) * K + kt * 32 + kg * 8);

    f32x4 acc[NT];
    #pragma unroll
    for (int nt = 0; nt < NT; ++nt){
      acc[nt][0] = biasv[nt]; acc[nt][1] = biasv[nt];
      acc[nt][2] = biasv[nt]; acc[nt][3] = biasv[nt];
    }
    #pragma unroll
    for (int nt = 0; nt < NT; ++nt)
      #pragma unroll
      for (int kt = 0; kt < KT; ++kt)
        acc[nt] = __builtin_amdgcn_mfma_f32_16x16x32_bf16(af[kt], bf[nt][kt], acc[nt], 0, 0, 0);

    if (wv < 3){
      ushort* out = (wv == 0) ? qo : (wv == 1) ? ko : vo;
      const int st = (wv == 0) ? FO : kvst;
      #pragma unroll
      for (int nt = 0; nt < NT; ++nt)
        #pragma unroll
        for (int i = 0; i < 4; ++i)
          out[(size_t)(row0 + kg * 4 + i) * st + nt * 16 + r16] = f2bf(acc[nt][i]);
    } else {
      #pragma unroll
      for (int nt = 0; nt < NT; ++nt)
        #pragma unroll
        for (int i = 0; i < 4; ++i)
          so[(size_t)(row0 + kg * 4 + i) * FO + nt * 16 + r16] = acc[nt][i];
    }
  }
}

// ---------------- attention: multi-node waves, batched edges ----------------

template<int FO, int G, int MODE>
__global__ __launch_bounds__(256) void k_attn2(
    const ushort* __restrict__ qb, const ushort* __restrict__ kv,
    const float* __restrict__ skip, const int* __restrict__ offs,
    const int* __restrict__ srclist, void* __restrict__ outp,
    int N, float scale)
{
  constexpr int LPN = FO / 4;
  constexpr int KVW = 2 * FO;
  constexpr int GPW = 64 / G;
  const int lane = threadIdx.x & 63;
  const int sub  = lane & (G - 1);
  const int gid  = lane / G;
  const int node = (blockIdx.x * (blockDim.x >> 6) + (threadIdx.x >> 6)) * GPW + gid;
  const bool nv  = node < N;
  const bool act = nv && (sub < LPN);
  const int sub2 = (sub < LPN) ? sub : 0;
  const int nodec = nv ? node : 0;

  ushort4 qw = *reinterpret_cast<const ushort4*>(qb + (size_t)nodec * FO + sub2 * 4);
  float qf[4];
  qf[0] = act ? bfu(qw.x) : 0.f;
  qf[1] = act ? bfu(qw.y) : 0.f;
  qf[2] = act ? bfu(qw.z) : 0.f;
  qf[3] = act ? bfu(qw.w) : 0.f;

  float m = -INFINITY, l = 0.f;
  float acc[4] = {0.f, 0.f, 0.f, 0.f};
  int e0 = nv ? offs[node] : 0;
  int e1 = nv ? offs[node + 1] : 0;

  uint2 kk[4], vv[4];
  auto LOAD = [&](int eb, uint2* K, uint2* V){
    #pragma unroll
    for (int i = 0; i < 4; ++i){
      int ee = eb + i;
      int ec = (ee < e1) ? ee : (e1 - 1);
      int j = srclist[ec];
      const ushort* r = kv + (size_t)j * KVW + sub2 * 4;
      K[i] = *reinterpret_cast<const uint2*>(r);
      V[i] = *reinterpret_cast<const uint2*>(r + FO);
    }
  };

  if (e0 < e1){
    LOAD(e0, kk, vv);
    for (int e = e0; e < e1; ){
      const int en = e + 4;
      const bool more = en < e1;
      uint2 kn[4], vn[4];
      if (more) LOAD(en, kn, vn);

      float s[4];
      #pragma unroll
      for (int i = 0; i < 4; ++i){
        uint a_ = kk[i].x, b_ = kk[i].y;
        s[i] = qf[0] * bf_lo(a_) + qf[1] * bf_hi(a_)
             + qf[2] * bf_lo(b_) + qf[3] * bf_hi(b_);
      }
      #pragma unroll
      for (int o = 1; o < G; o <<= 1){
        s[0] += __shfl_xor(s[0], o);
        s[1] += __shfl_xor(s[1], o);
        s[2] += __shfl_xor(s[2], o);
        s[3] += __shfl_xor(s[3], o);
      }
      s[0] = s[0] * scale;
      s[1] = (e + 1 < e1) ? s[1] * scale : -1e30f;
      s[2] = (e + 2 < e1) ? s[2] * scale : -1e30f;
      s[3] = (e + 3 < e1) ? s[3] * scale : -1e30f;

      float mnew = fmaxf(fmaxf(m, s[0]), fmaxf(fmaxf(s[1], s[2]), s[3]));
      float sfac = __expf(m - mnew);
      float p[4];
      p[0] = __expf(s[0] - mnew);
      p[1] = __expf(s[1] - mnew);
      p[2] = __expf(s[2] - mnew);
      p[3] = __expf(s[3] - mnew);
      l = l * sfac + (p[0] + p[1]) + (p[2] + p[3]);
      acc[0] *= sfac; acc[1] *= sfac; acc[2] *= sfac; acc[3] *= sfac;
      #pragma unroll
      for (int i = 0; i < 4; ++i){
        uint a_ = vv[i].x, b_ = vv[i].y;
        acc[0] = fmaf(p[i], bf_lo(a_), acc[0]);
        acc[1] = fmaf(p[i], bf_hi(a_), acc[1]);
        acc[2] = fmaf(p[i], bf_lo(b_), acc[2]);
        acc[3] = fmaf(p[i], bf_hi(b_), acc[3]);
      }
      m = mnew;
      e = en;
      if (more){
        #pragma unroll
        for (int i = 0; i < 4; ++i){ kk[i] = kn[i]; vv[i] = vn[i]; }
      }
    }
  }

  float inv = 1.f / fmaxf(l, 1e-16f);
  const float4 sv = *reinterpret_cast<const float4*>(skip + (size_t)nodec * FO + sub2 * 4);
  float val[4];
  val[0] = sv.x + acc[0] * inv;
  val[1] = sv.y + acc[1] * inv;
  val[2] = sv.z + acc[2] * inv;
  val[3] = sv.w + acc[3] * inv;

  if (MODE == 0){
    if (act){
      ushort4 o;
      o.x = f2bf(fmaxf(val[0], 0.f));
      o.y = f2bf(fmaxf(val[1], 0.f));
      o.z = f2bf(fmaxf(val[2], 0.f));
      o.w = f2bf(fmaxf(val[3], 0.f));
      *reinterpret_cast<ushort4*>((ushort*)outp + (size_t)node * FO + sub * 4) = o;
    }
  } else {
    float mx = act ? fmaxf(fmaxf(val[0], val[1]), fmaxf(val[2], val[3])) : -INFINITY;
    #pragma unroll
    for (int o = 1; o < G; o <<= 1) mx = fmaxf(mx, __shfl_xor(mx, o));
    float ssum = 0.f;
    if (act){
      ssum = __expf(val[0] - mx) + __expf(val[1] - mx)
           + __expf(val[2] - mx) + __expf(val[3] - mx);
    }
    #pragma unroll
    for (int o = 1; o < G; o <<= 1) ssum += __shfl_xor(ssum, o);
    float lg = __logf(ssum);
    if (act){
      float4 o;
      o.x = val[0] - mx - lg;
      o.y = val[1] - mx - lg;
      o.z = val[2] - mx - lg;
      o.w = val[3] - mx - lg;
      *reinterpret_cast<float4*>((float*)outp + (size_t)node * FO + sub * 4) = o;
    }
  }
}

// ---------------- launch ----------------

extern "C" void kernel_launch(void* const* d_in, const int* in_sizes, int n_in,
                              void* d_out, int out_size, void* d_ws, size_t ws_size,
                              hipStream_t stream)
{
  const float* x  = (const float*)d_in[0];
  const int*   ei = (const int*)d_in[1];
  const int N = in_sizes[0] / 128;
  const int E = in_sizes[1] / 2;

  const float* W1[4]; const float* b1[4];
  const float* W2[4]; const float* b2[4];
  const float* W3[4]; const float* b3[4];
  for (int i = 0; i < 4; ++i){
    W1[i] = (const float*)d_in[2 + i];   b1[i] = (const float*)d_in[6 + i];
    W2[i] = (const float*)d_in[10 + i];  b2[i] = (const float*)d_in[14 + i];
    W3[i] = (const float*)d_in[18 + i];  b3[i] = (const float*)d_in[22 + i];
  }

  size_t off = 0;
  auto alloc = [&](size_t bytes) -> void* {
    void* p = (char*)d_ws + off;
    off = (off + bytes + 255) & ~(size_t)255;
    return p;
  };
  int* offs    = (int*)alloc(((size_t)N + 1) * 4);
  int* cursor  = (int*)alloc((size_t)N * 4);
  int* srclist = (int*)alloc((size_t)E * 4);
  int* bsum    = (int*)alloc(1024 * 4);
  ushort* qb = (ushort*)alloc((size_t)N * 96 * 2);
  ushort* kvb = (ushort*)alloc((size_t)N * 192 * 2);
  float*  hF = (float*)alloc((size_t)N * 96 * 4);
  ushort* hb = (ushort*)alloc((size_t)N * 128 * 2);
  ushort* wb = (ushort*)alloc((size_t)98304 * 2);

  ushort* Wb1[4]; ushort* Wb2[4]; ushort* Wb3[4];
  for (int i = 0; i < 4; ++i){
    Wb1[i] = wb + (size_t)i * 12288;
    Wb2[i] = wb + 49152 + (size_t)i * 9216;
    Wb3[i] = wb + 49152 + 36864 + (size_t)i * 3072;
  }

  WSet wset;
  for (int i = 0; i < 4; ++i){
    wset.src[i]     = W1[i]; wset.dst[i]     = Wb1[i]; wset.n[i]     = 12288;
    wset.src[4 + i] = W2[i]; wset.dst[4 + i] = Wb2[i]; wset.n[4 + i] = 9216;
    wset.src[8 + i] = W3[i]; wset.dst[8 + i] = Wb3[i]; wset.n[8 + i] = 3072;
  }
  k_castw<<<dim3(48, 12), dim3(256), 0, stream>>>(wset);

  // --- CSR of incoming edges ---
  const int nb = (N + 1023) / 1024;
  hipMemsetAsync(cursor, 0, (size_t)N * sizeof(int), stream);
  k_hist<<<dim3((E + 255) / 256), dim3(256), 0, stream>>>(ei + E, cursor, E);
  k_scan_part<<<dim3(nb), dim3(256), 0, stream>>>(cursor, bsum, N);
  k_scan_mid<<<dim3(1), dim3(64), 0, stream>>>(bsum, nb);
  k_scan_add<<<dim3(nb), dim3(256), 0, stream>>>(cursor, offs, bsum, N, E);
  k_fill<<<dim3((E + 255) / 256), dim3(256), 0, stream>>>(ei, ei + E, cursor, srclist, E);

  k_castv<<<dim3(2048), dim3(256), 0, stream>>>(x, hb, N * 128 / 4);

  float* outf = (float*)d_out;
  const float sc96 = 1.0f / sqrtf(96.f);
  const float sc32 = 1.0f / sqrtf(32.f);

  // layer 1: K=128, FO=96
  k_projmfma<4, 6><<<dim3(1024), dim3(256), 0, stream>>>(hb, N,
      Wb1[0], Wb1[1], Wb1[2], Wb1[3], b1[0], b1[1], b1[2], b1[3],
      qb, kvb, kvb + 96, 192, hF);
  k_attn2<96, 32, 0><<<dim3(N / 8), dim3(256), 0, stream>>>(qb, kvb, hF, offs, srclist, hb, N, sc96);

  // layer 2: K=96, FO=96
  k_projmfma<3, 6><<<dim3(1024), dim3(256), 0, stream>>>(hb, N,
      Wb2[0], Wb2[1], Wb2[2], Wb2[3], b2[0], b2[1], b2[2], b2[3],
      qb, kvb, kvb + 96, 192, hF);
  k_attn2<96, 32, 0><<<dim3(N / 8), dim3(256), 0, stream>>>(qb, kvb, hF, offs, srclist, hb, N, sc96);

  // layer 3: K=96, FO=32 (+ fused log_softmax)
  k_projmfma<3, 2><<<dim3(1024), dim3(256), 0, stream>>>(hb, N,
      Wb3[0], Wb3[1], Wb3[2], Wb3[3], b3[0], b3[1], b3[2], b3[3],
      qb, kvb, kvb + 32, 64, hF);
  k_attn2<32, 16, 1><<<dim3(N / 16), dim3(256), 0, stream>>>(qb, kvb, hF, offs, srclist, outf, N, sc32);
}